// Round 4
// baseline (460.081 us; speedup 1.0000x reference)
//
#include <hip/hip_runtime.h>

typedef int         iv4 __attribute__((ext_vector_type(4)));
typedef float       fv4 __attribute__((ext_vector_type(4)));
typedef _Float16    hv4 __attribute__((ext_vector_type(4)));

// ---- folded weights: scorer(Linear 8->1) folded into the two node encoders ----
struct Fold {
    float va_s[4], va_d[4], vp_s[4], vp_d[4];
    float ca_s, ca_d, cp_s, cp_d;
};

__device__ inline Fold make_fold(const float* __restrict__ Wa, const float* __restrict__ ba,
                                 const float* __restrict__ Wp, const float* __restrict__ bp,
                                 const float* __restrict__ Ws) {
    Fold f;
    float w0 = Ws[0], w1 = Ws[1], w2 = Ws[2], w3 = Ws[3];
    float w4 = Ws[4], w5 = Ws[5], w6 = Ws[6], w7 = Ws[7];
#pragma unroll
    for (int j = 0; j < 4; ++j) {
        f.va_s[j] = w0*Wa[j] + w1*Wa[4+j] + w2*Wa[8+j] + w3*Wa[12+j];
        f.va_d[j] = w4*Wa[j] + w5*Wa[4+j] + w6*Wa[8+j] + w7*Wa[12+j];
        f.vp_s[j] = w0*Wp[j] + w1*Wp[4+j] + w2*Wp[8+j] + w3*Wp[12+j];
        f.vp_d[j] = w4*Wp[j] + w5*Wp[4+j] + w6*Wp[8+j] + w7*Wp[12+j];
    }
    f.ca_s = w0*ba[0] + w1*ba[1] + w2*ba[2] + w3*ba[3];
    f.ca_d = w4*ba[0] + w5*ba[1] + w6*ba[2] + w7*ba[3];
    f.cp_s = w0*bp[0] + w1*bp[1] + w2*bp[2] + w3*bp[3];
    f.cp_d = w4*bp[0] + w5*bp[1] + w6*bp[2] + w7*bp[3];
    return f;
}

__device__ inline void node_scores(const Fold& f, fv4 a, fv4 p,
                                   float& as, float& ps, float& ad, float& pd) {
    as = a.x*f.va_s[0] + a.y*f.va_s[1] + a.z*f.va_s[2] + a.w*f.va_s[3] + f.ca_s;
    ad = a.x*f.va_d[0] + a.y*f.va_d[1] + a.z*f.va_d[2] + a.w*f.va_d[3] + f.ca_d;
    ps = p.x*f.vp_s[0] + p.y*f.vp_s[1] + p.z*f.vp_s[2] + p.w*f.vp_s[3] + f.cp_s;
    pd = p.x*f.vp_d[0] + p.y*f.vp_d[1] + p.z*f.vp_d[2] + p.w*f.vp_d[3] + f.cp_d;
}

// ---- pass 1: pure node pass. NT loads, PLAIN stores (sc is re-read by pass 2
// immediately -> let it live in L2/L3 instead of round-tripping HBM). ----
__global__ __launch_bounds__(256) void node_pass1(
    const fv4* __restrict__ ax, const fv4* __restrict__ px,
    const float* __restrict__ Wa, const float* __restrict__ ba,
    const float* __restrict__ Wp, const float* __restrict__ bp,
    const float* __restrict__ Ws,
    hv4* __restrict__ sc, unsigned* __restrict__ maxes, int n)
{
    Fold f = make_fold(Wa, ba, Wp, bp, Ws);
    float ms = 0.f, md = 0.f;
    int stride = gridDim.x * blockDim.x;
    for (int i = blockIdx.x * blockDim.x + threadIdx.x; i < n; i += stride) {
        fv4 a = __builtin_nontemporal_load(ax + i);
        fv4 p = __builtin_nontemporal_load(px + i);
        float as, ps, ad, pd;
        node_scores(f, a, p, as, ps, ad, pd);
        hv4 h;
        h.x = (_Float16)as; h.y = (_Float16)ps; h.z = (_Float16)ad; h.w = (_Float16)pd;
        sc[i] = h;                                  // plain store: stays cached
        ms = fmaxf(ms, fmaxf(fabsf(as), fabsf(ps)));
        md = fmaxf(md, fmaxf(fabsf(ad), fabsf(pd)));
    }
#pragma unroll
    for (int off = 32; off >= 1; off >>= 1) {
        ms = fmaxf(ms, __shfl_down(ms, off));
        md = fmaxf(md, __shfl_down(md, off));
    }
    __shared__ float lms[4], lmd[4];
    int wave = threadIdx.x >> 6, lane = threadIdx.x & 63;
    if (lane == 0) { lms[wave] = ms; lmd[wave] = md; }
    __syncthreads();
    if (threadIdx.x == 0) {
        float bms = fmaxf(fmaxf(lms[0], lms[1]), fmaxf(lms[2], lms[3]));
        float bmd = fmaxf(fmaxf(lmd[0], lmd[1]), fmaxf(lmd[2], lmd[3]));
        atomicMax(&maxes[0], __float_as_uint(bms));  // positive floats order as uints
        atomicMax(&maxes[1], __float_as_uint(bmd));
    }
}

// ---- pass 2: 4 nodes/thread; fp16 scores -> two interleaved int8 tables
// (4 MB each, written plain so they seed L2/L3 for the gather passes). ----
__global__ __launch_bounds__(256) void node_pass2(
    const hv4* __restrict__ sc, const unsigned* __restrict__ maxes,
    unsigned long long* __restrict__ ts8, unsigned long long* __restrict__ td8, int n4)
{
    int i = blockIdx.x * blockDim.x + threadIdx.x;
    if (i >= n4) return;
    float inv_s = 127.f / fmaxf(__uint_as_float(maxes[0]), 1e-20f);
    float inv_d = 127.f / fmaxf(__uint_as_float(maxes[1]), 1e-20f);
    unsigned long long vs = 0, vd = 0;
#pragma unroll
    for (int j = 0; j < 4; ++j) {
        hv4 h = sc[4*i + j];
        int qas = min(127, max(-127, __float2int_rn((float)h.x * inv_s)));
        int qps = min(127, max(-127, __float2int_rn((float)h.y * inv_s)));
        int qad = min(127, max(-127, __float2int_rn((float)h.z * inv_d)));
        int qpd = min(127, max(-127, __float2int_rn((float)h.w * inv_d)));
        vs |= (unsigned long long)((unsigned)qas & 0xffu) << (16*j);
        vs |= (unsigned long long)((unsigned)qps & 0xffu) << (16*j + 8);
        vd |= (unsigned long long)((unsigned)qad & 0xffu) << (16*j);
        vd |= (unsigned long long)((unsigned)qpd & 0xffu) << (16*j + 8);
    }
    ts8[i] = vs;
    td8[i] = vd;
}

// ---- edge pass A: 8 edges/thread; reads et (once, streaming is free in a
// request-bound kernel), gathers src-role bytes, emits qsrc + dst-role bitmap ----
__global__ __launch_bounds__(256) void edge_src_pass(
    const iv4* __restrict__ src4, const iv4* __restrict__ et4,
    const int* __restrict__ esp, const int* __restrict__ edp,
    const signed char* __restrict__ ts,
    unsigned long long* __restrict__ qsrc,
    unsigned char* __restrict__ dbits, int n8)
{
    int i = blockIdx.x * blockDim.x + threadIdx.x;
    if (i >= n8) return;
    unsigned smask = (unsigned)((esp[0]&1) | ((esp[1]&1)<<1) | ((esp[2]&1)<<2) | ((esp[3]&1)<<3));
    unsigned dmask = (unsigned)((edp[0]&1) | ((edp[1]&1)<<1) | ((edp[2]&1)<<2) | ((edp[3]&1)<<3));

    iv4 s0 = __builtin_nontemporal_load(src4 + 2*i);
    iv4 s1 = __builtin_nontemporal_load(src4 + 2*i + 1);
    iv4 t0 = __builtin_nontemporal_load(et4 + 2*i);
    iv4 t1 = __builtin_nontemporal_load(et4 + 2*i + 1);
    int ty[8] = { t0.x&3, t0.y&3, t0.z&3, t0.w&3, t1.x&3, t1.y&3, t1.z&3, t1.w&3 };
    int sx[8] = { s0.x, s0.y, s0.z, s0.w, s1.x, s1.y, s1.z, s1.w };

    int a[8];
#pragma unroll
    for (int k = 0; k < 8; ++k) a[k] = 2*sx[k] + (int)((smask >> ty[k]) & 1u);

    int q[8];
#pragma unroll
    for (int k = 0; k < 8; ++k) q[k] = (int)ts[a[k]];   // 8 independent byte-gathers

    unsigned long long o = 0;
    unsigned db = 0;
#pragma unroll
    for (int k = 0; k < 8; ++k) {
        o |= (unsigned long long)((unsigned)q[k] & 0xffu) << (8*k);
        db |= ((dmask >> ty[k]) & 1u) << k;
    }
    __builtin_nontemporal_store(o, qsrc + i);
    __builtin_nontemporal_store((unsigned char)db, dbits + i);
}

// ---- edge pass B: 8 edges/thread; gathers dst-role bytes via bitmap, combines ----
__global__ __launch_bounds__(256) void edge_dst_pass(
    const iv4* __restrict__ dst4,
    const unsigned char* __restrict__ dbits,
    const float* __restrict__ bs, const unsigned* __restrict__ maxes,
    const signed char* __restrict__ td,
    const unsigned long long* __restrict__ qsrc,
    fv4* __restrict__ out4, int n8)
{
    int i = blockIdx.x * blockDim.x + threadIdx.x;
    if (i >= n8) return;
    float b = bs[0];
    float scale_s = __uint_as_float(maxes[0]) * (1.f / 127.f);
    float scale_d = __uint_as_float(maxes[1]) * (1.f / 127.f);

    iv4 d0 = __builtin_nontemporal_load(dst4 + 2*i);
    iv4 d1 = __builtin_nontemporal_load(dst4 + 2*i + 1);
    unsigned db = (unsigned)dbits[i];
    unsigned long long qq = qsrc[i];
    int dx[8] = { d0.x, d0.y, d0.z, d0.w, d1.x, d1.y, d1.z, d1.w };

    int a[8];
#pragma unroll
    for (int k = 0; k < 8; ++k) a[k] = 2*dx[k] + (int)((db >> k) & 1u);

    int qd[8];
#pragma unroll
    for (int k = 0; k < 8; ++k) qd[k] = (int)td[a[k]];  // 8 independent byte-gathers

    float r[8];
#pragma unroll
    for (int k = 0; k < 8; ++k) {
        int qs = (int)(signed char)((qq >> (8*k)) & 0xffull);
        r[k] = (float)qs * scale_s + (float)qd[k] * scale_d + b;
    }
    fv4 o0, o1;
    o0.x = r[0]; o0.y = r[1]; o0.z = r[2]; o0.w = r[3];
    o1.x = r[4]; o1.y = r[5]; o1.z = r[6]; o1.w = r[7];
    __builtin_nontemporal_store(o0, out4 + 2*i);
    __builtin_nontemporal_store(o1, out4 + 2*i + 1);
}

// ---- fallback (ws too small / unaligned sizes): fused per-edge path, f32 exact ----
__global__ __launch_bounds__(256) void fused_kernel(
    const fv4* __restrict__ ax, const fv4* __restrict__ px,
    const int* __restrict__ src, const int* __restrict__ dst, const int* __restrict__ et,
    const int* __restrict__ esp, const int* __restrict__ edp,
    const float* __restrict__ Wa, const float* __restrict__ ba,
    const float* __restrict__ Wp, const float* __restrict__ bp,
    const float* __restrict__ Ws, const float* __restrict__ bs,
    float* __restrict__ out, int n)
{
    int e = blockIdx.x * blockDim.x + threadIdx.x;
    if (e >= n) return;
    Fold f = make_fold(Wa, ba, Wp, bp, Ws);
    int t = et[e];
    int sp = esp[t] & 1, dp = edp[t] & 1;
    fv4 sv = sp ? px[src[e]] : ax[src[e]];
    fv4 dv = dp ? px[dst[e]] : ax[dst[e]];
    float ssc = sp ? (sv.x*f.vp_s[0] + sv.y*f.vp_s[1] + sv.z*f.vp_s[2] + sv.w*f.vp_s[3] + f.cp_s)
                   : (sv.x*f.va_s[0] + sv.y*f.va_s[1] + sv.z*f.va_s[2] + sv.w*f.va_s[3] + f.ca_s);
    float dsc = dp ? (dv.x*f.vp_d[0] + dv.y*f.vp_d[1] + dv.z*f.vp_d[2] + dv.w*f.vp_d[3] + f.cp_d)
                   : (dv.x*f.va_d[0] + dv.y*f.va_d[1] + dv.z*f.va_d[2] + dv.w*f.va_d[3] + f.ca_d);
    out[e] = ssc + dsc + bs[0];
}

extern "C" void kernel_launch(void* const* d_in, const int* in_sizes, int n_in,
                              void* d_out, int out_size, void* d_ws, size_t ws_size,
                              hipStream_t stream) {
    const float* ax  = (const float*)d_in[0];
    const float* px  = (const float*)d_in[1];
    const int*   src = (const int*)d_in[2];
    const int*   dst = (const int*)d_in[3];
    const int*   et  = (const int*)d_in[4];
    const int*   esp = (const int*)d_in[5];
    const int*   edp = (const int*)d_in[6];
    const float* Wa  = (const float*)d_in[7];
    const float* ba  = (const float*)d_in[8];
    const float* Wp  = (const float*)d_in[9];
    const float* bp  = (const float*)d_in[10];
    const float* Ws  = (const float*)d_in[11];
    const float* bs  = (const float*)d_in[12];
    float* out = (float*)d_out;

    const int n_nodes = in_sizes[0] / 4;
    const int n_edges = in_sizes[2];

    // ws layout:
    //   [0,256):       maxes (2 x u32)
    //   [256, +U):     union { fp16 scores (8N) ; qsrc (E) }   (sc dead after pass2)
    //   [.., +2N):     ts (int8, interleaved author/paper, src role; 4 MB -> L2)
    //   [.., +2N):     td (dst role; 4 MB -> L2)
    //   [.., +E/8):    dbits (dst-role bit per edge, built by edge_src_pass)
    auto rnd = [](size_t v) { return (v + 255) & ~(size_t)255; };
    size_t union_sz = rnd((size_t)n_edges > (size_t)n_nodes * 8 ? (size_t)n_edges
                                                                : (size_t)n_nodes * 8);
    const size_t off_u  = 256;
    const size_t off_ts = off_u + union_sz;
    const size_t off_td = off_ts + rnd((size_t)n_nodes * 2);
    const size_t off_db = off_td + rnd((size_t)n_nodes * 2);
    const size_t need   = off_db + rnd((size_t)(n_edges / 8) + 1);

    if (ws_size >= need && (n_edges & 7) == 0 && (n_nodes & 3) == 0) {
        unsigned* maxes = (unsigned*)d_ws;
        hv4* sc = (hv4*)((char*)d_ws + off_u);
        unsigned long long* qsrc = (unsigned long long*)((char*)d_ws + off_u); // aliases sc
        signed char* ts = (signed char*)((char*)d_ws + off_ts);
        signed char* td = (signed char*)((char*)d_ws + off_td);
        unsigned char* dbits = (unsigned char*)((char*)d_ws + off_db);

        (void)hipMemsetAsync(maxes, 0, 2 * sizeof(unsigned), stream);
        node_pass1<<<2048, 256, 0, stream>>>(
            (const fv4*)ax, (const fv4*)px, Wa, ba, Wp, bp, Ws, sc, maxes, n_nodes);
        const int n4 = n_nodes / 4;
        node_pass2<<<(n4 + 255) / 256, 256, 0, stream>>>(
            sc, maxes, (unsigned long long*)ts, (unsigned long long*)td, n4);

        const int n8 = n_edges / 8;
        const int nb = (n8 + 255) / 256;
        edge_src_pass<<<nb, 256, 0, stream>>>(
            (const iv4*)src, (const iv4*)et, esp, edp, ts, qsrc, dbits, n8);
        edge_dst_pass<<<nb, 256, 0, stream>>>(
            (const iv4*)dst, dbits, bs, maxes, td, qsrc, (fv4*)out, n8);
    } else {
        fused_kernel<<<(n_edges + 255) / 256, 256, 0, stream>>>(
            (const fv4*)ax, (const fv4*)px, src, dst, et, esp, edp,
            Wa, ba, Wp, bp, Ws, bs, out, n_edges);
    }
}

// Round 5
// 432.788 us; speedup vs baseline: 1.0631x; 1.0631x over previous
//
#include <hip/hip_runtime.h>

typedef int         iv4 __attribute__((ext_vector_type(4)));
typedef float       fv4 __attribute__((ext_vector_type(4)));

// ---- folded weights: scorer(Linear 8->1) folded into the two node encoders ----
struct Fold {
    float va_s[4], va_d[4], vp_s[4], vp_d[4];
    float ca_s, ca_d, cp_s, cp_d;
};

__device__ inline Fold make_fold(const float* __restrict__ Wa, const float* __restrict__ ba,
                                 const float* __restrict__ Wp, const float* __restrict__ bp,
                                 const float* __restrict__ Ws) {
    Fold f;
    float w0 = Ws[0], w1 = Ws[1], w2 = Ws[2], w3 = Ws[3];
    float w4 = Ws[4], w5 = Ws[5], w6 = Ws[6], w7 = Ws[7];
#pragma unroll
    for (int j = 0; j < 4; ++j) {
        f.va_s[j] = w0*Wa[j] + w1*Wa[4+j] + w2*Wa[8+j] + w3*Wa[12+j];
        f.va_d[j] = w4*Wa[j] + w5*Wa[4+j] + w6*Wa[8+j] + w7*Wa[12+j];
        f.vp_s[j] = w0*Wp[j] + w1*Wp[4+j] + w2*Wp[8+j] + w3*Wp[12+j];
        f.vp_d[j] = w4*Wp[j] + w5*Wp[4+j] + w6*Wp[8+j] + w7*Wp[12+j];
    }
    f.ca_s = w0*ba[0] + w1*ba[1] + w2*ba[2] + w3*ba[3];
    f.ca_d = w4*ba[0] + w5*ba[1] + w6*ba[2] + w7*ba[3];
    f.cp_s = w0*bp[0] + w1*bp[1] + w2*bp[2] + w3*bp[3];
    f.cp_d = w4*bp[0] + w5*bp[1] + w6*bp[2] + w7*bp[3];
    return f;
}

__device__ inline void node_scores(const Fold& f, fv4 a, fv4 p,
                                   float& as, float& ps, float& ad, float& pd) {
    as = a.x*f.va_s[0] + a.y*f.va_s[1] + a.z*f.va_s[2] + a.w*f.va_s[3] + f.ca_s;
    ad = a.x*f.va_d[0] + a.y*f.va_d[1] + a.z*f.va_d[2] + a.w*f.va_d[3] + f.ca_d;
    ps = p.x*f.vp_s[0] + p.y*f.vp_s[1] + p.z*f.vp_s[2] + p.w*f.vp_s[3] + f.cp_s;
    pd = p.x*f.vp_d[0] + p.y*f.vp_d[1] + p.z*f.vp_d[2] + p.w*f.vp_d[3] + f.cp_d;
}

#define P1_BLOCKS 2048

// ---- pass 1: max-only. PLAIN loads (seed L3 for pass 2's re-read); per-block
// maxes to a 16 KB array -> no memset dispatch, no atomics. ----
__global__ __launch_bounds__(256) void node_pass1(
    const fv4* __restrict__ ax, const fv4* __restrict__ px,
    const float* __restrict__ Wa, const float* __restrict__ ba,
    const float* __restrict__ Wp, const float* __restrict__ bp,
    const float* __restrict__ Ws,
    float* __restrict__ bms, float* __restrict__ bmd, int n)
{
    Fold f = make_fold(Wa, ba, Wp, bp, Ws);
    float ms = 0.f, md = 0.f;
    int stride = gridDim.x * blockDim.x;
    for (int i = blockIdx.x * blockDim.x + threadIdx.x; i < n; i += stride) {
        fv4 a = ax[i];
        fv4 p = px[i];
        float as, ps, ad, pd;
        node_scores(f, a, p, as, ps, ad, pd);
        ms = fmaxf(ms, fmaxf(fabsf(as), fabsf(ps)));
        md = fmaxf(md, fmaxf(fabsf(ad), fabsf(pd)));
    }
#pragma unroll
    for (int off = 32; off >= 1; off >>= 1) {
        ms = fmaxf(ms, __shfl_down(ms, off));
        md = fmaxf(md, __shfl_down(md, off));
    }
    __shared__ float lms[4], lmd[4];
    int wave = threadIdx.x >> 6, lane = threadIdx.x & 63;
    if (lane == 0) { lms[wave] = ms; lmd[wave] = md; }
    __syncthreads();
    if (threadIdx.x == 0) {
        bms[blockIdx.x] = fmaxf(fmaxf(lms[0], lms[1]), fmaxf(lms[2], lms[3]));
        bmd[blockIdx.x] = fmaxf(fmaxf(lmd[0], lmd[1]), fmaxf(lmd[2], lmd[3]));
    }
}

// ---- pass 2: reduce block-maxes (prologue), recompute scores from L3-hot
// ax/px, quantize, write the two interleaved int8 tables (4 MB each). ----
__global__ __launch_bounds__(256) void node_pass2(
    const fv4* __restrict__ ax, const fv4* __restrict__ px,
    const float* __restrict__ Wa, const float* __restrict__ ba,
    const float* __restrict__ Wp, const float* __restrict__ bp,
    const float* __restrict__ Ws,
    const float* __restrict__ bms, const float* __restrict__ bmd, int nblk,
    float* __restrict__ maxf,
    unsigned long long* __restrict__ ts8, unsigned long long* __restrict__ td8, int n4)
{
    // --- prologue: every thread participates (no early return before syncs) ---
    float ms = 0.f, md = 0.f;
    for (int j = threadIdx.x; j < nblk; j += 256) {
        ms = fmaxf(ms, bms[j]);
        md = fmaxf(md, bmd[j]);
    }
#pragma unroll
    for (int off = 32; off >= 1; off >>= 1) {
        ms = fmaxf(ms, __shfl_down(ms, off));
        md = fmaxf(md, __shfl_down(md, off));
    }
    __shared__ float lms[4], lmd[4], fin[2];
    int wave = threadIdx.x >> 6, lane = threadIdx.x & 63;
    if (lane == 0) { lms[wave] = ms; lmd[wave] = md; }
    __syncthreads();
    if (threadIdx.x == 0) {
        float gs = fmaxf(fmaxf(lms[0], lms[1]), fmaxf(lms[2], lms[3]));
        float gd = fmaxf(fmaxf(lmd[0], lmd[1]), fmaxf(lmd[2], lmd[3]));
        fin[0] = gs; fin[1] = gd;
        if (blockIdx.x == 0) { maxf[0] = gs; maxf[1] = gd; }  // for edge_dst_pass
    }
    __syncthreads();
    float inv_s = 127.f / fmaxf(fin[0], 1e-20f);
    float inv_d = 127.f / fmaxf(fin[1], 1e-20f);

    int i = blockIdx.x * blockDim.x + threadIdx.x;
    if (i >= n4) return;
    Fold f = make_fold(Wa, ba, Wp, bp, Ws);
    unsigned long long vs = 0, vd = 0;
#pragma unroll
    for (int j = 0; j < 4; ++j) {
        fv4 a = ax[4*i + j];
        fv4 p = px[4*i + j];
        float as, ps, ad, pd;
        node_scores(f, a, p, as, ps, ad, pd);
        int qas = min(127, max(-127, __float2int_rn(as * inv_s)));
        int qps = min(127, max(-127, __float2int_rn(ps * inv_s)));
        int qad = min(127, max(-127, __float2int_rn(ad * inv_d)));
        int qpd = min(127, max(-127, __float2int_rn(pd * inv_d)));
        vs |= (unsigned long long)((unsigned)qas & 0xffu) << (16*j);
        vs |= (unsigned long long)((unsigned)qps & 0xffu) << (16*j + 8);
        vd |= (unsigned long long)((unsigned)qad & 0xffu) << (16*j);
        vd |= (unsigned long long)((unsigned)qpd & 0xffu) << (16*j + 8);
    }
    ts8[i] = vs;
    td8[i] = vd;
}

// ---- edge pass A (unchanged from best-known): 8 edges/thread; gathers
// src-role bytes from 4 MB L2-resident table; emits qsrc + dst-role bitmap ----
__global__ __launch_bounds__(256) void edge_src_pass(
    const iv4* __restrict__ src4, const iv4* __restrict__ et4,
    const int* __restrict__ esp, const int* __restrict__ edp,
    const signed char* __restrict__ ts,
    unsigned long long* __restrict__ qsrc,
    unsigned char* __restrict__ dbits, int n8)
{
    int i = blockIdx.x * blockDim.x + threadIdx.x;
    if (i >= n8) return;
    unsigned smask = (unsigned)((esp[0]&1) | ((esp[1]&1)<<1) | ((esp[2]&1)<<2) | ((esp[3]&1)<<3));
    unsigned dmask = (unsigned)((edp[0]&1) | ((edp[1]&1)<<1) | ((edp[2]&1)<<2) | ((edp[3]&1)<<3));

    iv4 s0 = __builtin_nontemporal_load(src4 + 2*i);
    iv4 s1 = __builtin_nontemporal_load(src4 + 2*i + 1);
    iv4 t0 = __builtin_nontemporal_load(et4 + 2*i);
    iv4 t1 = __builtin_nontemporal_load(et4 + 2*i + 1);
    int ty[8] = { t0.x&3, t0.y&3, t0.z&3, t0.w&3, t1.x&3, t1.y&3, t1.z&3, t1.w&3 };
    int sx[8] = { s0.x, s0.y, s0.z, s0.w, s1.x, s1.y, s1.z, s1.w };

    int a[8];
#pragma unroll
    for (int k = 0; k < 8; ++k) a[k] = 2*sx[k] + (int)((smask >> ty[k]) & 1u);

    int q[8];
#pragma unroll
    for (int k = 0; k < 8; ++k) q[k] = (int)ts[a[k]];   // 8 independent byte-gathers

    unsigned long long o = 0;
    unsigned db = 0;
#pragma unroll
    for (int k = 0; k < 8; ++k) {
        o |= (unsigned long long)((unsigned)q[k] & 0xffu) << (8*k);
        db |= ((dmask >> ty[k]) & 1u) << k;
    }
    __builtin_nontemporal_store(o, qsrc + i);
    __builtin_nontemporal_store((unsigned char)db, dbits + i);
}

// ---- edge pass B (unchanged): 8 edges/thread; gathers dst-role bytes, combines ----
__global__ __launch_bounds__(256) void edge_dst_pass(
    const iv4* __restrict__ dst4,
    const unsigned char* __restrict__ dbits,
    const float* __restrict__ bs, const float* __restrict__ maxf,
    const signed char* __restrict__ td,
    const unsigned long long* __restrict__ qsrc,
    fv4* __restrict__ out4, int n8)
{
    int i = blockIdx.x * blockDim.x + threadIdx.x;
    if (i >= n8) return;
    float b = bs[0];
    float scale_s = maxf[0] * (1.f / 127.f);
    float scale_d = maxf[1] * (1.f / 127.f);

    iv4 d0 = __builtin_nontemporal_load(dst4 + 2*i);
    iv4 d1 = __builtin_nontemporal_load(dst4 + 2*i + 1);
    unsigned db = (unsigned)dbits[i];
    unsigned long long qq = qsrc[i];
    int dx[8] = { d0.x, d0.y, d0.z, d0.w, d1.x, d1.y, d1.z, d1.w };

    int a[8];
#pragma unroll
    for (int k = 0; k < 8; ++k) a[k] = 2*dx[k] + (int)((db >> k) & 1u);

    int qd[8];
#pragma unroll
    for (int k = 0; k < 8; ++k) qd[k] = (int)td[a[k]];  // 8 independent byte-gathers

    float r[8];
#pragma unroll
    for (int k = 0; k < 8; ++k) {
        int qs = (int)(signed char)((qq >> (8*k)) & 0xffull);
        r[k] = (float)qs * scale_s + (float)qd[k] * scale_d + b;
    }
    fv4 o0, o1;
    o0.x = r[0]; o0.y = r[1]; o0.z = r[2]; o0.w = r[3];
    o1.x = r[4]; o1.y = r[5]; o1.z = r[6]; o1.w = r[7];
    __builtin_nontemporal_store(o0, out4 + 2*i);
    __builtin_nontemporal_store(o1, out4 + 2*i + 1);
}

// ---- fallback (ws too small / unaligned sizes): fused per-edge path, f32 exact ----
__global__ __launch_bounds__(256) void fused_kernel(
    const fv4* __restrict__ ax, const fv4* __restrict__ px,
    const int* __restrict__ src, const int* __restrict__ dst, const int* __restrict__ et,
    const int* __restrict__ esp, const int* __restrict__ edp,
    const float* __restrict__ Wa, const float* __restrict__ ba,
    const float* __restrict__ Wp, const float* __restrict__ bp,
    const float* __restrict__ Ws, const float* __restrict__ bs,
    float* __restrict__ out, int n)
{
    int e = blockIdx.x * blockDim.x + threadIdx.x;
    if (e >= n) return;
    Fold f = make_fold(Wa, ba, Wp, bp, Ws);
    int t = et[e];
    int sp = esp[t] & 1, dp = edp[t] & 1;
    fv4 sv = sp ? px[src[e]] : ax[src[e]];
    fv4 dv = dp ? px[dst[e]] : ax[dst[e]];
    float ssc = sp ? (sv.x*f.vp_s[0] + sv.y*f.vp_s[1] + sv.z*f.vp_s[2] + sv.w*f.vp_s[3] + f.cp_s)
                   : (sv.x*f.va_s[0] + sv.y*f.va_s[1] + sv.z*f.va_s[2] + sv.w*f.va_s[3] + f.ca_s);
    float dsc = dp ? (dv.x*f.vp_d[0] + dv.y*f.vp_d[1] + dv.z*f.vp_d[2] + dv.w*f.vp_d[3] + f.cp_d)
                   : (dv.x*f.va_d[0] + dv.y*f.va_d[1] + dv.z*f.va_d[2] + dv.w*f.va_d[3] + f.ca_d);
    out[e] = ssc + dsc + bs[0];
}

extern "C" void kernel_launch(void* const* d_in, const int* in_sizes, int n_in,
                              void* d_out, int out_size, void* d_ws, size_t ws_size,
                              hipStream_t stream) {
    const float* ax  = (const float*)d_in[0];
    const float* px  = (const float*)d_in[1];
    const int*   src = (const int*)d_in[2];
    const int*   dst = (const int*)d_in[3];
    const int*   et  = (const int*)d_in[4];
    const int*   esp = (const int*)d_in[5];
    const int*   edp = (const int*)d_in[6];
    const float* Wa  = (const float*)d_in[7];
    const float* ba  = (const float*)d_in[8];
    const float* Wp  = (const float*)d_in[9];
    const float* bp  = (const float*)d_in[10];
    const float* Ws  = (const float*)d_in[11];
    const float* bs  = (const float*)d_in[12];
    float* out = (float*)d_out;

    const int n_nodes = in_sizes[0] / 4;
    const int n_edges = in_sizes[2];

    // ws layout:
    //   [0, 8K):       bms (per-block max, src role)   [P1_BLOCKS floats]
    //   [8K, 16K):     bmd (per-block max, dst role)
    //   [16K, +256):   maxf (2 floats, final maxes, published by pass2 blk 0)
    //   [.., +E):      qsrc (1 B per edge)
    //   [.., +2N):     ts (int8, interleaved author/paper, src role; 4 MB -> L2)
    //   [.., +2N):     td (dst role; 4 MB -> L2)
    //   [.., +E/8):    dbits (dst-role bit per edge, built by edge_src_pass)
    auto rnd = [](size_t v) { return (v + 255) & ~(size_t)255; };
    const size_t off_bms = 0;
    const size_t off_bmd = off_bms + rnd((size_t)P1_BLOCKS * 4);
    const size_t off_mx  = off_bmd + rnd((size_t)P1_BLOCKS * 4);
    const size_t off_q   = off_mx + 256;
    const size_t off_ts  = off_q + rnd((size_t)n_edges);
    const size_t off_td  = off_ts + rnd((size_t)n_nodes * 2);
    const size_t off_db  = off_td + rnd((size_t)n_nodes * 2);
    const size_t need    = off_db + rnd((size_t)(n_edges / 8) + 1);

    if (ws_size >= need && (n_edges & 7) == 0 && (n_nodes & 3) == 0) {
        float* bms = (float*)((char*)d_ws + off_bms);
        float* bmd = (float*)((char*)d_ws + off_bmd);
        float* maxf = (float*)((char*)d_ws + off_mx);
        unsigned long long* qsrc = (unsigned long long*)((char*)d_ws + off_q);
        signed char* ts = (signed char*)((char*)d_ws + off_ts);
        signed char* td = (signed char*)((char*)d_ws + off_td);
        unsigned char* dbits = (unsigned char*)((char*)d_ws + off_db);

        node_pass1<<<P1_BLOCKS, 256, 0, stream>>>(
            (const fv4*)ax, (const fv4*)px, Wa, ba, Wp, bp, Ws, bms, bmd, n_nodes);
        const int n4 = n_nodes / 4;
        node_pass2<<<(n4 + 255) / 256, 256, 0, stream>>>(
            (const fv4*)ax, (const fv4*)px, Wa, ba, Wp, bp, Ws,
            bms, bmd, P1_BLOCKS, maxf,
            (unsigned long long*)ts, (unsigned long long*)td, n4);

        const int n8 = n_edges / 8;
        const int nb = (n8 + 255) / 256;
        edge_src_pass<<<nb, 256, 0, stream>>>(
            (const iv4*)src, (const iv4*)et, esp, edp, ts, qsrc, dbits, n8);
        edge_dst_pass<<<nb, 256, 0, stream>>>(
            (const iv4*)dst, dbits, bs, maxf, td, qsrc, (fv4*)out, n8);
    } else {
        fused_kernel<<<(n_edges + 255) / 256, 256, 0, stream>>>(
            (const fv4*)ax, (const fv4*)px, src, dst, et, esp, edp,
            Wa, ba, Wp, bp, Ws, bs, out, n_edges);
    }
}